// Round 1
// baseline (1602.428 us; speedup 1.0000x reference)
//
#include <hip/hip_runtime.h>
#include <math.h>

// Problem constants (from reference)
#define B_Q   64
#define K_A   4096
#define DIMV  50257
#define QSTR  50260          // padded qlog row stride (multiple of 4 -> 16B aligned rows)
#define NK    8              // split-K chunks
#define KCH   6400           // k-chunk length, multiple of DT (=> aligned float4 loads)
#define DT    128            // LDS k-stage depth
#define LROW  132            // padded LDS row stride in floats (16B-aligned, bank-friendly)
#define TN    64             // anchors per block

// ---------------- qlog precompute ----------------
__global__ void qlog_k(const float* __restrict__ q, float* __restrict__ ql) {
    int col = blockIdx.x * 256 + threadIdx.x;
    int row = blockIdx.y;
    if (col < DIMV)
        ql[row * QSTR + col] = logf(q[row * DIMV + col] + 1e-10f);
}

// ---------------- main split-K GEMM + self-term ----------------
// grid: (K_A/TN, NK), block: 256
// cpart: [NK][B_Q][K_A]  partial cross sums (unscaled)
// spart: [NK][K_A]       partial self-term sums (unscaled)
__global__ __launch_bounds__(256, 2)
void gemm_k(const float* __restrict__ ql, const float* __restrict__ anc,
            float* __restrict__ cpart, float* __restrict__ spart)
{
    __shared__ float qlds[B_Q * LROW];
    __shared__ float alds[TN * LROW];

    const int t    = threadIdx.x;
    const int n0   = blockIdx.x * TN;
    const int c    = blockIdx.y;
    const int kend = min(DIMV, (c + 1) * KCH);

    const int bq   = t >> 4;    // 0..15 : query-row group
    const int nq   = t & 15;    // 0..15 : anchor-row group
    const int col4 = t & 31;    // staging float4 column
    const int row0 = t >> 5;    // staging row base (0..7)

    float acc[4][4];
#pragma unroll
    for (int i = 0; i < 4; i++)
#pragma unroll
        for (int j = 0; j < 4; j++) acc[i][j] = 0.f;
    float sacc[8];
#pragma unroll
    for (int j = 0; j < 8; j++) sacc[j] = 0.f;

    for (int kb = c * KCH; kb < kend; kb += DT) {
        // ---- stage qlog tile [64][DT] (aligned float4 from padded ws) ----
#pragma unroll
        for (int j = 0; j < 8; j++) {
            const int r = row0 + 8 * j;
            const int d = kb + 4 * col4;
            float4 v;
            if (d + 4 <= kend) {
                v = *(const float4*)(ql + r * QSTR + d);
            } else {
                v.x = (d + 0 < kend) ? ql[r * QSTR + d + 0] : 0.f;
                v.y = (d + 1 < kend) ? ql[r * QSTR + d + 1] : 0.f;
                v.z = (d + 2 < kend) ? ql[r * QSTR + d + 2] : 0.f;
                v.w = (d + 3 < kend) ? ql[r * QSTR + d + 3] : 0.f;
            }
            *(float4*)(qlds + r * LROW + 4 * col4) = v;
        }
        // ---- stage anchor tile [64][DT] + fold self-term ----
#pragma unroll
        for (int j = 0; j < 8; j++) {
            const int r = row0 + 8 * j;
            const int d = kb + 4 * col4;
            const float* ap = anc + (size_t)(n0 + r) * DIMV + d;
            float a0 = (d + 0 < kend) ? ap[0] : 0.f;
            float a1 = (d + 1 < kend) ? ap[1] : 0.f;
            float a2 = (d + 2 < kend) ? ap[2] : 0.f;
            float a3 = (d + 3 < kend) ? ap[3] : 0.f;
            float4 v; v.x = a0; v.y = a1; v.z = a2; v.w = a3;
            *(float4*)(alds + r * LROW + 4 * col4) = v;
            sacc[j] += a0 * logf(a0 + 1e-10f) + a1 * logf(a1 + 1e-10f)
                     + a2 * logf(a2 + 1e-10f) + a3 * logf(a3 + 1e-10f);
        }
        __syncthreads();

        // ---- compute: 64 FMA per 4-k step per thread ----
#pragma unroll 4
        for (int k0 = 0; k0 < DT; k0 += 4) {
            float4 qv[4], av[4];
#pragma unroll
            for (int i = 0; i < 4; i++)
                qv[i] = *(const float4*)(qlds + (bq + 16 * i) * LROW + k0);
#pragma unroll
            for (int j = 0; j < 4; j++)
                av[j] = *(const float4*)(alds + (nq + 16 * j) * LROW + k0);
#pragma unroll
            for (int i = 0; i < 4; i++)
#pragma unroll
                for (int j = 0; j < 4; j++) {
                    acc[i][j] += qv[i].x * av[j].x;
                    acc[i][j] += qv[i].y * av[j].y;
                    acc[i][j] += qv[i].z * av[j].z;
                    acc[i][j] += qv[i].w * av[j].w;
                }
        }
        __syncthreads();
    }

    // ---- write cross partials (coalesced over nq) ----
#pragma unroll
    for (int i = 0; i < 4; i++)
#pragma unroll
        for (int j = 0; j < 4; j++)
            cpart[(size_t)(c * B_Q + bq + 16 * i) * K_A + n0 + nq + 16 * j] = acc[i][j];

    // ---- self-term: reduce over the 32 threads sharing each staged row ----
#pragma unroll
    for (int j = 0; j < 8; j++) {
        float s = sacc[j];
#pragma unroll
        for (int m = 16; m > 0; m >>= 1) s += __shfl_xor(s, m, 64);
        if (col4 == 0) spart[c * K_A + n0 + row0 + 8 * j] = s;
    }
}

// ---------------- top-8 + majority vote ----------------
// grid: B_Q blocks, 256 threads
__global__ void topk_k(const float* __restrict__ cpart, const float* __restrict__ spart,
                       const int* __restrict__ labels, int* __restrict__ out)
{
    __shared__ float vals[K_A];
    __shared__ float rmin[256];
    __shared__ int   ridx[256];
    __shared__ int   chosen[8];

    const int b = blockIdx.x;
    const int t = threadIdx.x;

    // assemble kl row with a FIXED deterministic summation order
    for (int k = t; k < K_A; k += 256) {
        float s = 0.f, cr = 0.f;
#pragma unroll
        for (int c = 0; c < NK; c++) {
            s  += spart[c * K_A + k];
            cr += cpart[(size_t)(c * B_Q + b) * K_A + k];
        }
        vals[k] = s - cr;   // unscaled kl (monotonic in true kl)
    }
    __syncthreads();

    for (int it = 0; it < 8; it++) {
        float mv = INFINITY; int mi = 1 << 30;
        for (int k = t; k < K_A; k += 256) {   // ascending k: lower index wins ties
            float v = vals[k];
            if (v < mv) { mv = v; mi = k; }
        }
        rmin[t] = mv; ridx[t] = mi;
        __syncthreads();
        for (int s = 128; s > 0; s >>= 1) {
            if (t < s) {
                float v2 = rmin[t + s]; int i2 = ridx[t + s];
                if (v2 < rmin[t] || (v2 == rmin[t] && i2 < ridx[t])) {
                    rmin[t] = v2; ridx[t] = i2;
                }
            }
            __syncthreads();
        }
        if (t == 0) { chosen[it] = ridx[0]; vals[ridx[0]] = INFINITY; }
        __syncthreads();
    }

    if (t == 0) {
        int cnt1 = 0;
#pragma unroll
        for (int it = 0; it < 8; it++) cnt1 += labels[chosen[it]];
        // argmax([cnt0, cnt1]) : class 1 only on strict majority (tie -> 0)
        out[b] = (cnt1 >= 5) ? 1 : 0;
    }
}

extern "C" void kernel_launch(void* const* d_in, const int* in_sizes, int n_in,
                              void* d_out, int out_size, void* d_ws, size_t ws_size,
                              hipStream_t stream) {
    const float* query  = (const float*)d_in[0];   // [64][50257] f32
    const float* anchor = (const float*)d_in[1];   // [4096][50257] f32
    const int*   labels = (const int*)d_in[2];     // [4096] i32
    int* out = (int*)d_out;                        // [64] i32 predictions

    char* ws = (char*)d_ws;
    float* ql    = (float*)ws;                                  // 64*50260*4   = 12,866,560 B
    float* cpart = (float*)(ws + 12866560);                     // 8*64*4096*4  =  8,388,608 B
    float* spart = (float*)(ws + 12866560 + 8388608);           // 8*4096*4     =    131,072 B

    qlog_k<<<dim3((DIMV + 255) / 256, B_Q), 256, 0, stream>>>(query, ql);
    gemm_k<<<dim3(K_A / TN, NK), 256, 0, stream>>>(ql, anchor, cpart, spart);
    topk_k<<<B_Q, 256, 0, stream>>>(cpart, spart, labels, out);
}

// Round 2
// 1352.559 us; speedup vs baseline: 1.1847x; 1.1847x over previous
//
#include <hip/hip_runtime.h>
#include <math.h>

// Problem constants
#define B_Q   64
#define K_A   4096
#define DIMV  50257
#define KPAD  50688          // = 512*99, multiple of NK*DT
#define NK    8              // split-K chunks
#define KCH   6336           // KPAD/NK, = 99*DT
#define DT    64             // k depth per LDS stage
#define LR    72             // LDS row stride in bf16 elements (144 B)
#define TN    64             // anchors per block

typedef short bf16x8 __attribute__((ext_vector_type(8)));
typedef float f32x4  __attribute__((ext_vector_type(4)));

static __device__ __forceinline__ unsigned short f2bf(float x) {
    unsigned int u = __builtin_bit_cast(unsigned int, x);
    unsigned int r = u + 0x7FFFu + ((u >> 16) & 1u);   // RTNE
    return (unsigned short)(r >> 16);
}
static __device__ __forceinline__ float bf2f(unsigned short h) {
    unsigned int u = ((unsigned int)h) << 16;
    return __builtin_bit_cast(float, u);
}

// ---------------- query log + hi/lo split ----------------
// grid (KPAD/256, B_Q), block 256
__global__ void qprep_k(const float* __restrict__ q,
                        unsigned short* __restrict__ qh,
                        unsigned short* __restrict__ ql) {
    int col = blockIdx.x * 256 + threadIdx.x;
    int row = blockIdx.y;
    float x = 0.f;
    if (col < DIMV) x = logf(q[row * DIMV + col] + 1e-10f);
    unsigned short h = f2bf(x);
    unsigned short l = f2bf(x - bf2f(h));
    qh[row * KPAD + col] = h;
    ql[row * KPAD + col] = l;
}

// ---------------- MFMA split-K GEMM + self-term ----------------
// grid (K_A/TN, NK), block 256 (4 waves)
// cpart: [NK][B_Q][K_A] fp32 partial cross sums; spart: [NK][K_A]
__global__ __launch_bounds__(256, 2)
void gemm_k(const unsigned short* __restrict__ qh_g,
            const unsigned short* __restrict__ ql_g,
            const float* __restrict__ anc,
            float* __restrict__ cpart, float* __restrict__ spart)
{
    __shared__ __align__(16) unsigned short qh_s[B_Q * LR];
    __shared__ __align__(16) unsigned short ql_s[B_Q * LR];
    __shared__ __align__(16) unsigned short ah_s[TN * LR];
    __shared__ __align__(16) unsigned short al_s[TN * LR];

    const int t    = threadIdx.x;
    const int n0   = blockIdx.x * TN;
    const int c    = blockIdx.y;
    const int lane = t & 63;
    const int m0   = (t >> 6) * 16;          // wave's query-row base
    const int l15  = lane & 15;
    const int q4   = lane >> 4;

    f32x4 acc[4];
#pragma unroll
    for (int i = 0; i < 4; i++) acc[i] = (f32x4){0.f, 0.f, 0.f, 0.f};
    float sacc[4] = {0.f, 0.f, 0.f, 0.f};

    const int arow = t >> 4;                 // 0..15, anchor staging row base
    const int ac4  = (t & 15) * 4;           // anchor staging col (floats)

    for (int kb = c * KCH; kb < (c + 1) * KCH; kb += DT) {
        // ---- stage queries (precomputed bf16 hi/lo), 16B chunks ----
#pragma unroll
        for (int j = 0; j < 4; j++) {
            int idx = t + 256 * j;           // 0..1023
            int sel = idx >> 9;              // 0 = hi, 1 = lo
            int rem = idx & 511;
            int row = rem >> 3;
            int g   = rem & 7;
            const unsigned short* src = (sel ? ql_g : qh_g) + (size_t)row * KPAD + kb + g * 8;
            unsigned short* dst = (sel ? ql_s : qh_s) + row * LR + g * 8;
            *(uint4*)dst = *(const uint4*)src;
        }
        // ---- stage anchors: fp32 -> bf16 hi/lo + self-term ----
        const bool full = (kb + DT <= DIMV);
#pragma unroll
        for (int j = 0; j < 4; j++) {
            const int r = arow + 16 * j;
            const int d = kb + ac4;
            const float* ap = anc + (size_t)(n0 + r) * DIMV + d;
            float a0, a1, a2, a3;
            if (full) {
                float4 v = *(const float4*)ap;
                a0 = v.x; a1 = v.y; a2 = v.z; a3 = v.w;
            } else {
                a0 = (d + 0 < DIMV) ? ap[0] : 0.f;
                a1 = (d + 1 < DIMV) ? ap[1] : 0.f;
                a2 = (d + 2 < DIMV) ? ap[2] : 0.f;
                a3 = (d + 3 < DIMV) ? ap[3] : 0.f;
            }
            sacc[j] += a0 * logf(a0 + 1e-10f) + a1 * logf(a1 + 1e-10f)
                     + a2 * logf(a2 + 1e-10f) + a3 * logf(a3 + 1e-10f);
            ushort4 hv, lv;
            hv.x = f2bf(a0); lv.x = f2bf(a0 - bf2f(hv.x));
            hv.y = f2bf(a1); lv.y = f2bf(a1 - bf2f(hv.y));
            hv.z = f2bf(a2); lv.z = f2bf(a2 - bf2f(hv.z));
            hv.w = f2bf(a3); lv.w = f2bf(a3 - bf2f(hv.w));
            *(ushort4*)(ah_s + r * LR + ac4) = hv;
            *(ushort4*)(al_s + r * LR + ac4) = lv;
        }
        __syncthreads();

        // ---- MFMA: 2 k-steps of 32, 4 anchor tiles, 3 terms ----
#pragma unroll
        for (int ks = 0; ks < DT; ks += 32) {
            const int koff = ks + q4 * 8;
            bf16x8 a_h = *(const bf16x8*)(qh_s + (m0 + l15) * LR + koff);
            bf16x8 a_l = *(const bf16x8*)(ql_s + (m0 + l15) * LR + koff);
#pragma unroll
            for (int tl = 0; tl < 4; tl++) {
                bf16x8 b_h = *(const bf16x8*)(ah_s + (16 * tl + l15) * LR + koff);
                bf16x8 b_l = *(const bf16x8*)(al_s + (16 * tl + l15) * LR + koff);
                acc[tl] = __builtin_amdgcn_mfma_f32_16x16x32_bf16(a_h, b_h, acc[tl], 0, 0, 0);
                acc[tl] = __builtin_amdgcn_mfma_f32_16x16x32_bf16(a_h, b_l, acc[tl], 0, 0, 0);
                acc[tl] = __builtin_amdgcn_mfma_f32_16x16x32_bf16(a_l, b_h, acc[tl], 0, 0, 0);
            }
        }
        __syncthreads();
    }

    // ---- write cross partials (C/D layout: col=lane&15, row=quad*4+reg) ----
#pragma unroll
    for (int tl = 0; tl < 4; tl++)
#pragma unroll
        for (int r = 0; r < 4; r++) {
            int m = m0 + q4 * 4 + r;
            int n = n0 + 16 * tl + l15;
            cpart[((size_t)(c * B_Q + m)) * K_A + n] = acc[tl][r];
        }

    // ---- self-term: reduce over the 16 threads sharing each staged row ----
#pragma unroll
    for (int j = 0; j < 4; j++) {
        float s = sacc[j];
#pragma unroll
        for (int m = 1; m <= 8; m <<= 1) s += __shfl_xor(s, m, 64);
        if ((t & 15) == 0) spart[c * K_A + n0 + arow + 16 * j] = s;
    }
}

// ---------------- top-8 + majority vote ----------------
__global__ void topk_k(const float* __restrict__ cpart, const float* __restrict__ spart,
                       const int* __restrict__ labels, int* __restrict__ out)
{
    __shared__ float vals[K_A];
    __shared__ float rmin[256];
    __shared__ int   ridx[256];
    __shared__ int   chosen[8];

    const int b = blockIdx.x;
    const int t = threadIdx.x;

    for (int k = t; k < K_A; k += 256) {
        float s = 0.f, cr = 0.f;
#pragma unroll
        for (int c = 0; c < NK; c++) {
            s  += spart[c * K_A + k];
            cr += cpart[(size_t)(c * B_Q + b) * K_A + k];
        }
        vals[k] = s - cr;   // unscaled kl (monotonic)
    }
    __syncthreads();

    for (int it = 0; it < 8; it++) {
        float mv = INFINITY; int mi = 1 << 30;
        for (int k = t; k < K_A; k += 256) {
            float v = vals[k];
            if (v < mv) { mv = v; mi = k; }
        }
        rmin[t] = mv; ridx[t] = mi;
        __syncthreads();
        for (int s = 128; s > 0; s >>= 1) {
            if (t < s) {
                float v2 = rmin[t + s]; int i2 = ridx[t + s];
                if (v2 < rmin[t] || (v2 == rmin[t] && i2 < ridx[t])) {
                    rmin[t] = v2; ridx[t] = i2;
                }
            }
            __syncthreads();
        }
        if (t == 0) { chosen[it] = ridx[0]; vals[ridx[0]] = INFINITY; }
        __syncthreads();
    }

    if (t == 0) {
        int cnt1 = 0;
#pragma unroll
        for (int it = 0; it < 8; it++) cnt1 += labels[chosen[it]];
        out[b] = (cnt1 >= 5) ? 1 : 0;   // argmax([cnt0,cnt1]), tie -> 0
    }
}

extern "C" void kernel_launch(void* const* d_in, const int* in_sizes, int n_in,
                              void* d_out, int out_size, void* d_ws, size_t ws_size,
                              hipStream_t stream) {
    const float* query  = (const float*)d_in[0];
    const float* anchor = (const float*)d_in[1];
    const int*   labels = (const int*)d_in[2];
    int* out = (int*)d_out;

    char* ws = (char*)d_ws;
    unsigned short* qh = (unsigned short*)ws;                        // 64*50688*2 = 6,488,064
    unsigned short* ql = (unsigned short*)(ws + 6488064);            // 6,488,064
    float* cpart = (float*)(ws + 12976128);                          // 8*64*4096*4 = 8,388,608
    float* spart = (float*)(ws + 12976128 + 8388608);                // 131,072

    qprep_k<<<dim3(KPAD / 256, B_Q), 256, 0, stream>>>(query, qh, ql);
    gemm_k<<<dim3(K_A / TN, NK), 256, 0, stream>>>(qh, ql, anchor, cpart, spart);
    topk_k<<<B_Q, 256, 0, stream>>>(cpart, spart, labels, out);
}